// Round 1
// baseline (506.301 us; speedup 1.0000x reference)
//
#include <hip/hip_runtime.h>

#define T_LEN 1024
#define P_DIM 32
#define HOME_IDX 0

// One wave (64 threads) per batch. Lanes: p = lane&31 (state), h = lane>>5
// (which half of the 32 predecessors q this lane scans).
// Exactness notes:
//  * NEG = finfo(f32).min/4 = -8.507059e37; ulp(NEG) ~ 1e31 >> |A|<=0.01, so
//    NEG + A[q][p] == NEG exactly => the v=0 slice is NEG except q=HOME, so
//    v0[p] = delta0_home + A[0][p] and a0 = 0 exactly (HOME=0 is first index).
//  * argmax first-index semantics: within-half ascending scan with strict '>',
//    cross-half / cross-lane combine with lexicographic (val desc, idx asc).
//  * use1 = (v1 > v0) strict, matching the reference.
__launch_bounds__(64, 1)
__global__ void crf_viterbi_kernel(const float* __restrict__ U,
                                   const float* __restrict__ A,
                                   const float* __restrict__ bias,
                                   int* __restrict__ out,
                                   int T)
{
    __shared__ __align__(16) float sdelta[P_DIM];
    __shared__ unsigned char spsi[(T_LEN - 1) * P_DIM];   // 32736 bytes

    const int b    = blockIdx.x;
    const int lane = threadIdx.x;
    const int p    = lane & 31;
    const int h    = lane >> 5;
    const float NEG = -(3.4028234663852886e38f / 4.0f);

    // Preload A fragment: A[q][p] for q = 16*h + j
    float Areg[16];
#pragma unroll
    for (int j = 0; j < 16; ++j)
        Areg[j] = A[(16 * h + j) * P_DIM + p];
    const float A0p    = A[p];        // A[HOME][p]
    const float A00    = A[0];        // A[HOME][HOME]
    const float bias_p = bias[p];
    const float bias0  = bias[0];

    const float* __restrict__ Ub = U + (size_t)b * T * P_DIM;

    // t = 0 init
    float u0      = Ub[p] + bias_p;
    float delta1  = (p == HOME_IDX) ? NEG : u0;   // v=1 slice, per-lane p
    float delta0h = Ub[HOME_IDX] + bias0;         // v=0 slice at HOME (uniform)

    sdelta[p] = delta1;     // both halves write identical data
    __syncthreads();

    float u_cur = Ub[P_DIM + p];   // U[t=1, p]

    for (int t = 1; t < T; ++t) {
        // prefetch next step's unary
        int tn = (t + 1 < T) ? (t + 1) : t;
        float u_next = Ub[(size_t)tn * P_DIM + p];

        // broadcast-read delta1[q], q = 16*h + j  (uniform addr per half)
        float dq[16];
#pragma unroll
        for (int jj = 0; jj < 4; ++jj) {
            float4 v4 = *reinterpret_cast<const float4*>(&sdelta[16 * h + 4 * jj]);
            dq[4 * jj + 0] = v4.x;
            dq[4 * jj + 1] = v4.y;
            dq[4 * jj + 2] = v4.z;
            dq[4 * jj + 3] = v4.w;
        }

        // candidates + first-index argmax within this half's 16 q's
        float bv = dq[0] + Areg[0];
        int   bi = 16 * h;
#pragma unroll
        for (int j = 1; j < 16; ++j) {
            float c = dq[j] + Areg[j];
            bool  g = c > bv;           // strict: keep earlier q on ties
            bv = g ? c : bv;
            bi = g ? (16 * h + j) : bi;
        }
        // cross-half combine (lexicographic: larger val, then smaller idx)
        {
            float ov = __shfl_xor(bv, 32);
            int   oi = __shfl_xor(bi, 32);
            bool take = (ov > bv) || ((ov == bv) && (oi < bi));
            bv = take ? ov : bv;
            bi = take ? oi : bi;
        }
        float v1 = bv;
        int   a1 = bi;

        float v0   = delta0h + A0p;
        bool  use1 = v1 > v0;            // strict, matches reference
        float bval = use1 ? v1 : v0;
        int   bq   = use1 ? a1 : 0;      // a0 == 0 exactly
        int   bvv  = use1 ? 1 : 0;

        bool  is_home = (p == HOME_IDX);
        float sel = is_home ? v1 : bval;
        int   p1  = is_home ? a1 : bq;
        int   vv1 = is_home ? 1  : bvv;

        float Ut  = u_cur + bias_p;
        float dn1 = sel + Ut;

        // v=0 chain update (wave-uniform): dn0[HOME] = (delta0h + A00) + Ut[HOME]
        float Ut0 = __shfl(Ut, 0);
        delta0h = (delta0h + A00) + Ut0;

        __syncthreads();   // reads of sdelta done before overwrite (WAR)
        sdelta[p] = dn1;
        spsi[(t - 1) * P_DIM + p] = (unsigned char)(p1 | (vv1 << 5));
        __syncthreads();   // write visible before next iter's reads (RAW)

        delta1 = dn1;
        u_cur  = u_next;
    }

    // last_p = argmax_p delta_T[:,1], first index wins (lexicographic butterfly)
    float mv = delta1;
    int   mi = p;
#pragma unroll
    for (int m = 16; m >= 1; m >>= 1) {
        float ov = __shfl_xor(mv, m);
        int   oi = __shfl_xor(mi, m);
        bool take = (ov > mv) || ((ov == mv) && (oi < mi));
        mv = take ? ov : mv;
        mi = take ? oi : mi;
    }
    const int last_p = mi;

    int* __restrict__ outb = out + (size_t)b * T;
    if (lane == 0) {
        outb[T - 1] = last_p;
        int y = last_p, v = 1;
        for (int i = T - 2; i >= 0; --i) {
            int byte = spsi[i * P_DIM + y];
            int py = v ? (byte & 31) : 0;
            int nv = v ? ((byte >> 5) & 1) : 0;
            outb[i] = py;
            y = py;
            v = nv;
        }
    }
}

extern "C" void kernel_launch(void* const* d_in, const int* in_sizes, int n_in,
                              void* d_out, int out_size, void* d_ws, size_t ws_size,
                              hipStream_t stream) {
    const float* U    = (const float*)d_in[0];   // (B, T, P) f32
    const float* A    = (const float*)d_in[1];   // (P, P)    f32
    const float* bias = (const float*)d_in[2];   // (P,)      f32
    int* out = (int*)d_out;                      // (B, T)    int32

    const int B = in_sizes[0] / (T_LEN * P_DIM);
    crf_viterbi_kernel<<<B, 64, 0, stream>>>(U, A, bias, out, T_LEN);
}